// Round 5
// baseline (849.682 us; speedup 1.0000x reference)
//
#include <hip/hip_runtime.h>
#include <hip/hip_bf16.h>

typedef __bf16 bf16;
typedef __bf16 bf16x8 __attribute__((ext_vector_type(8)));
typedef float  floatx4 __attribute__((ext_vector_type(4)));

#define AS1 __attribute__((address_space(1)))
#define AS3 __attribute__((address_space(3)))

#define B_    2
#define S_    2048
#define D_    2048
#define H_    16
#define KVH_  8
#define DH_   128
#define M_    4096      // B_*S_
#define NQKV_ 4096      // D_ + 2*KVH_*DH_

#define CHUNK_ 12       // k-tiles (of 64 keys) per flash block
#define NSLOT_ 60       // sum over qt of ceil((qt+1)/CHUNK_) = 12 + 24 + 24
#define NBLK_  (NSLOT_ * 32)   // 1920 flash blocks

// ---------------------------------------------------------------- cast fp32 -> bf16
__global__ __launch_bounds__(256) void cast_kernel(const float* __restrict__ in,
                                                   bf16* __restrict__ out, int n) {
    int i = (blockIdx.x * blockDim.x + threadIdx.x) * 4;
    if (i < n) {
        float4 v = *(const float4*)(in + i);
        union { bf16 h[4]; double d; } u;
        u.h[0] = (bf16)v.x; u.h[1] = (bf16)v.y; u.h[2] = (bf16)v.z; u.h[3] = (bf16)v.w;
        *(double*)(out + i) = u.d;
    }
}

// ---------------------------------------------------------------- RoPE tables [S][64]
__global__ __launch_bounds__(256) void rope_table(float* __restrict__ cost,
                                                  float* __restrict__ sint) {
    int i = blockIdx.x * blockDim.x + threadIdx.x;   // S_*64 threads
    int t = i >> 6, fi = i & 63;
    float inv = expf(-9.210340371976184f * (float)fi * (1.0f / 64.0f)); // 10000^(-fi/64)
    float ang = (float)t * inv;
    cost[i] = cosf(ang);
    sint[i] = sinf(ang);
}

// ---------------------------------------------------------------- GEMM: C[M,N] = A[M,K] * B[N,K]^T   (bf16 in, fp32 acc, CT out)
#define BM 128
#define BN 128
#define BK 64
template <typename CT>
__global__ __launch_bounds__(256) void gemm_bt(const bf16* __restrict__ A,
                                               const bf16* __restrict__ Bw,
                                               CT* __restrict__ C,
                                               int M, int N, int K) {
    __shared__ __align__(16) bf16 Als[BM * BK];
    __shared__ __align__(16) bf16 Bls[BN * BK];
    int tid  = threadIdx.x;
    int wave = tid >> 6, lane = tid & 63;
    int quad = lane >> 4, l16 = lane & 15;
    int wm = (wave >> 1) << 6;   // 0 / 64
    int wn = (wave & 1) << 6;

    long bm0 = (long)blockIdx.y * BM;
    long bn0 = (long)blockIdx.x * BN;
    const bf16* Ab = A  + bm0 * K;
    const bf16* Bb = Bw + bn0 * K;

    int srow = wave * 32 + (lane >> 3);
    int scol = ((lane & 7) ^ (lane >> 3)) << 3;
    int sdst = (wave * 32 + (lane >> 3)) * BK + ((lane & 7) << 3);

    floatx4 acc[4][4] = {};

    for (int k0 = 0; k0 < K; k0 += BK) {
        #pragma unroll
        for (int i = 0; i < 4; ++i) {
            const bf16* ga = Ab + (long)(srow + i * 8) * K + k0 + scol;
            const bf16* gb = Bb + (long)(srow + i * 8) * K + k0 + scol;
            __builtin_amdgcn_global_load_lds((AS1 const unsigned int*)ga,
                                             (AS3 unsigned int*)(Als + sdst + i * 512), 16, 0, 0);
            __builtin_amdgcn_global_load_lds((AS1 const unsigned int*)gb,
                                             (AS3 unsigned int*)(Bls + sdst + i * 512), 16, 0, 0);
        }
        __syncthreads();
        #pragma unroll
        for (int ks = 0; ks < 2; ++ks) {
            bf16x8 af[4], bfr[4];
            #pragma unroll
            for (int t = 0; t < 4; ++t) {
                int row = wm + t * 16 + l16;
                int g = (ks * 4 + quad) ^ (row & 7);
                af[t] = *(const bf16x8*)(Als + row * BK + (g << 3));
            }
            #pragma unroll
            for (int t = 0; t < 4; ++t) {
                int row = wn + t * 16 + l16;
                int g = (ks * 4 + quad) ^ (row & 7);
                bfr[t] = *(const bf16x8*)(Bls + row * BK + (g << 3));
            }
            #pragma unroll
            for (int mt = 0; mt < 4; ++mt)
                #pragma unroll
                for (int nt = 0; nt < 4; ++nt)
                    acc[mt][nt] = __builtin_amdgcn_mfma_f32_16x16x32_bf16(af[mt], bfr[nt], acc[mt][nt], 0, 0, 0);
        }
        __syncthreads();
    }
    #pragma unroll
    for (int mt = 0; mt < 4; ++mt) {
        #pragma unroll
        for (int nt = 0; nt < 4; ++nt) {
            long row = bm0 + wm + mt * 16 + quad * 4;
            long col = bn0 + wn + nt * 16 + l16;
            #pragma unroll
            for (int r = 0; r < 4; ++r)
                C[(row + r) * N + col] = (CT)acc[mt][nt][r];
        }
    }
}

// ---------------------------------------------------------------- canon_b + RMSNorm + RoPE
__global__ __launch_bounds__(512) void canon_kernel(const bf16* __restrict__ QKV,
                                                    const float* __restrict__ wq,
                                                    const float* __restrict__ wk,
                                                    const float* __restrict__ wv,
                                                    const float* __restrict__ qnw,
                                                    const float* __restrict__ knw,
                                                    const float* __restrict__ cost,
                                                    const float* __restrict__ sint,
                                                    bf16* __restrict__ qf,
                                                    bf16* __restrict__ kf,
                                                    bf16* __restrict__ vf) {
    int row = blockIdx.x;
    int b = row >> 11, t = row & 2047;
    int tid = threadIdx.x;
    int c0 = tid << 3;
    __shared__ float vals[4096];
    __shared__ float rrms[24];

    const float* wrow; int cw;
    if (c0 < 2048)      { wrow = wq; cw = c0; }
    else if (c0 < 3072) { wrow = wk; cw = c0 - 2048; }
    else                { wrow = wv; cw = c0 - 3072; }

    float4 w4[8];
    #pragma unroll
    for (int j = 0; j < 8; ++j) w4[j] = *(const float4*)(wrow + (cw + j) * 4);

    union U8 { float4 v; bf16 h[8]; };
    float acc[8];
    {
        U8 u; u.v = *(const float4*)(QKV + (size_t)row * 4096 + c0);
        #pragma unroll
        for (int j = 0; j < 8; ++j) acc[j] = (float)u.h[j];
    }
    #pragma unroll
    for (int kk = 0; kk < 4; ++kk) {
        int tt = t - kk;
        if (tt >= 0) {
            U8 u; u.v = *(const float4*)(QKV + ((size_t)((b << 11) + tt)) * 4096 + c0);
            #pragma unroll
            for (int j = 0; j < 8; ++j) acc[j] += (&w4[j].x)[kk] * (float)u.h[j];
        }
    }
    #pragma unroll
    for (int j = 0; j < 8; ++j) vals[c0 + j] = acc[j];
    __syncthreads();

    if (tid < 384) {
        int hh = tid >> 4, sub = tid & 15;
        const float* vp = vals + hh * 128 + sub * 8;
        float ss = 0.f;
        #pragma unroll
        for (int j = 0; j < 8; ++j) ss += vp[j] * vp[j];
        ss += __shfl_xor(ss, 1); ss += __shfl_xor(ss, 2);
        ss += __shfl_xor(ss, 4); ss += __shfl_xor(ss, 8);
        if (sub == 0) rrms[hh] = rsqrtf(ss * (1.0f / 128.0f) + 1e-6f);
    }
    __syncthreads();

    if (c0 < 3072) {
        int ch   = (c0 < 2048) ? c0 : c0 - 2048;
        int head = ch >> 7;
        int j0   = ch & 127;
        int hb   = c0 - j0;
        const float* nw = (c0 < 2048) ? qnw : knw;
        float r1 = rrms[c0 >> 7];
        const float* ct = cost + t * 64;
        const float* st = sint + t * 64;
        __align__(16) bf16 outv[8];
        #pragma unroll
        for (int j = 0; j < 8; ++j) {
            int jj = j0 + j;
            float xn = vals[hb + jj] * r1 * nw[jj];
            int pj = (jj < 64) ? jj + 64 : jj - 64;
            float xp = vals[hb + pj] * r1 * nw[pj];
            float rot = (jj < 64) ? -xp : xp;
            int fi = jj & 63;
            outv[j] = (bf16)(xn * ct[fi] + rot * st[fi]);
        }
        bf16* dst = (c0 < 2048)
            ? qf + ((((size_t)b * H_  + head) * S_ + t) << 7) + j0
            : kf + ((((size_t)b * KVH_ + head) * S_ + t) << 7) + j0;
        *(float4*)dst = *(float4*)outv;
    } else {
        int ch = c0 - 3072;
        int head = ch >> 7, j0 = ch & 127;
        __align__(16) bf16 outv[8];
        #pragma unroll
        for (int j = 0; j < 8; ++j) outv[j] = (bf16)acc[j];
        bf16* dst = vf + ((((size_t)b * KVH_ + head) * S_ + t) << 7) + j0;
        *(float4*)dst = *(float4*)outv;
    }
}

// ---------------------------------------------------------------- V transpose: [bk][S][128] -> [bk][128][S]
__global__ __launch_bounds__(256) void transpose_v(const bf16* __restrict__ vf,
                                                   bf16* __restrict__ vfT) {
    __shared__ __align__(16) bf16 tile[64][72];
    int bk = blockIdx.z;
    int t0 = blockIdx.x * 64;
    int d0 = blockIdx.y * 64;
    int tid = threadIdx.x;
    const bf16* src = vf + ((size_t)bk * S_ << 7);
    {
        int r = tid >> 3, cs = (tid & 7) << 3;
        #pragma unroll
        for (int p = 0; p < 2; ++p)
            *(float4*)(&tile[r + p * 32][cs]) =
                *(const float4*)(src + (size_t)(t0 + r + p * 32) * 128 + d0 + cs);
    }
    __syncthreads();
    {
        int dr = tid >> 3, ts = (tid & 7) << 3;
        #pragma unroll
        for (int p = 0; p < 2; ++p) {
            __align__(16) bf16 outv[8];
            #pragma unroll
            for (int j = 0; j < 8; ++j) outv[j] = tile[ts + j][dr + p * 32];
            *(float4*)(vfT + ((size_t)bk * 128 + d0 + dr + p * 32) * S_ + t0 + ts) = *(float4*)outv;
        }
    }
}

// ---------------------------------------------------------------- flash attention, split-K chunks
// Block = (b, h, q-tile qt, chunk c of <=CHUNK_ k-tiles). Barrier-free, 4 waves.
// Writes normalized partial o (bf16) + (m, l) per row; combine kernel reduces.
__global__ __launch_bounds__(256, 4) void flash_attn(const bf16* __restrict__ qf,
                                                     const bf16* __restrict__ kf,
                                                     const bf16* __restrict__ vfT,
                                                     bf16* __restrict__ opart,
                                                     float2* __restrict__ mlbuf) {
    __shared__ __align__(16) bf16 Pls[4][16][72];
    int bid = blockIdx.x;                  // [0, NBLK_)
    int bh = bid & 31, j = bid >> 5;       // bh -> XCD spread; j in [0,60)
    int b = bh >> 4, h = bh & 15, kvh = h >> 1;
    int qt, c;
    if (j < 12)      { qt = j;                  c = 0; }
    else if (j < 36) { qt = 12 + ((j - 12) >> 1); c = (j - 12) & 1; }
    else             { qt = 24 + (j - 36) / 3;  c = (j - 36) % 3; }
    int kt0 = c * CHUNK_;
    int kt1 = min(kt0 + CHUNK_, qt + 1);

    int tid = threadIdx.x, wave = tid >> 6, lane = tid & 63;
    int quad = lane >> 4, l16 = lane & 15;
    int qrow0 = (qt << 6) + (wave << 4);

    const bf16* kbase = kf  + (((size_t)b * KVH_ + kvh) * S_ << 7);
    const bf16* vbase = vfT + (((size_t)b * KVH_ + kvh) << 7) * S_;

    bf16x8 aq[4];
    {
        const bf16* qr = qf + ((((size_t)b * H_ + h) * S_ + qrow0 + l16) << 7) + (quad << 3);
        #pragma unroll
        for (int ks = 0; ks < 4; ++ks) aq[ks] = *(const bf16x8*)(qr + ks * 32);
    }
    floatx4 o[8] = {};
    float m_i[4] = {-1e30f, -1e30f, -1e30f, -1e30f};
    float l_i[4] = {0.f, 0.f, 0.f, 0.f};
    const float scl2 = 0.08838834764831845f * 1.4426950408889634f;  // scale*log2(e)

    for (int kt = kt0; kt < kt1; ++kt) {
        int kb = kt << 6;
        // S = Q K^T
        floatx4 sc[4] = {};
        #pragma unroll
        for (int nt = 0; nt < 4; ++nt) {
            const bf16* kr = kbase + ((size_t)(kb + nt * 16 + l16) << 7) + (quad << 3);
            #pragma unroll
            for (int ks = 0; ks < 4; ++ks) {
                bf16x8 kb8 = *(const bf16x8*)(kr + ks * 32);
                sc[nt] = __builtin_amdgcn_mfma_f32_16x16x32_bf16(aq[ks], kb8, sc[nt], 0, 0, 0);
            }
        }
        // prefetch V frags for ks=0 (independent of softmax -> hides L2 latency)
        bf16x8 vpre[8];
        #pragma unroll
        for (int dnt = 0; dnt < 8; ++dnt)
            vpre[dnt] = *(const bf16x8*)(vbase + (size_t)(dnt * 16 + l16) * S_ + kb + (quad << 3));
        // scale (log2 domain) + causal mask
        int qr0 = qrow0 + (quad << 2);
        #pragma unroll
        for (int nt = 0; nt < 4; ++nt) {
            int key = kb + nt * 16 + l16;
            #pragma unroll
            for (int r = 0; r < 4; ++r) {
                float s = sc[nt][r] * scl2;
                sc[nt][r] = (key <= qr0 + r) ? s : -1e30f;
            }
        }
        // online softmax
        #pragma unroll
        for (int r = 0; r < 4; ++r) {
            float mx = fmaxf(fmaxf(sc[0][r], sc[1][r]), fmaxf(sc[2][r], sc[3][r]));
            mx = fmaxf(mx, __shfl_xor(mx, 1)); mx = fmaxf(mx, __shfl_xor(mx, 2));
            mx = fmaxf(mx, __shfl_xor(mx, 4)); mx = fmaxf(mx, __shfl_xor(mx, 8));
            float mnew = fmaxf(m_i[r], mx);
            float alpha = exp2f(m_i[r] - mnew);
            m_i[r] = mnew;
            float sum = 0.f;
            #pragma unroll
            for (int nt = 0; nt < 4; ++nt) {
                float pv = exp2f(sc[nt][r] - mnew);
                sc[nt][r] = pv;
                sum += pv;
            }
            sum += __shfl_xor(sum, 1); sum += __shfl_xor(sum, 2);
            sum += __shfl_xor(sum, 4); sum += __shfl_xor(sum, 8);
            l_i[r] = l_i[r] * alpha + sum;
            #pragma unroll
            for (int dnt = 0; dnt < 8; ++dnt) o[dnt][r] *= alpha;
            #pragma unroll
            for (int nt = 0; nt < 4; ++nt)
                Pls[wave][(quad << 2) + r][nt * 16 + l16] = (bf16)sc[nt][r];
        }
        // O += P V  (ks=0 from prefetch, ks=1 inline)
        {
            bf16x8 pa = *(const bf16x8*)(&Pls[wave][l16][(quad << 3)]);
            #pragma unroll
            for (int dnt = 0; dnt < 8; ++dnt)
                o[dnt] = __builtin_amdgcn_mfma_f32_16x16x32_bf16(pa, vpre[dnt], o[dnt], 0, 0, 0);
            bf16x8 pb = *(const bf16x8*)(&Pls[wave][l16][32 + (quad << 3)]);
            #pragma unroll
            for (int dnt = 0; dnt < 8; ++dnt) {
                bf16x8 vb = *(const bf16x8*)(vbase + (size_t)(dnt * 16 + l16) * S_
                                             + kb + 32 + (quad << 3));
                o[dnt] = __builtin_amdgcn_mfma_f32_16x16x32_bf16(pb, vb, o[dnt], 0, 0, 0);
            }
        }
    }
    // epilogue: normalized partial õ + (m,l)
    bf16* op = opart + (((size_t)bid * 64 + (wave << 4)) << 7);
    #pragma unroll
    for (int r = 0; r < 4; ++r) {
        int lrow = (quad << 2) + r;
        float rl = 1.0f / l_i[r];
        #pragma unroll
        for (int dnt = 0; dnt < 8; ++dnt)
            op[lrow * 128 + dnt * 16 + l16] = (bf16)(o[dnt][r] * rl);
        if (l16 == 0)
            mlbuf[(size_t)bid * 64 + (wave << 4) + lrow] = make_float2(m_i[r], l_i[r]);
    }
}

// ---------------------------------------------------------------- combine partials -> attn[B][S][H*128]
__global__ __launch_bounds__(256) void combine_kernel(const bf16* __restrict__ opart,
                                                      const float2* __restrict__ mlbuf,
                                                      bf16* __restrict__ attn) {
    int tid = threadIdx.x;
    int lr = tid >> 6, lane = tid & 63;
    int rid = blockIdx.x * 4 + lr;           // [0, B*S*H)
    int h = rid & 15, bq = rid >> 4;
    int b = bq >> 11, q = bq & 2047;
    int qt = q >> 6, r64 = q & 63;
    int bh = (b << 4) + h;
    int C, jb;
    if (qt < 12)      { C = 1; jb = qt; }
    else if (qt < 24) { C = 2; jb = 12 + 2 * (qt - 12); }
    else              { C = 3; jb = 36 + 3 * (qt - 24); }

    float2 ml[3];
    float M = -1e30f;
    for (int cc = 0; cc < C; ++cc) {
        int slot = (jb + cc) * 32 + bh;
        ml[cc] = mlbuf[(size_t)slot * 64 + r64];
        M = fmaxf(M, ml[cc].x);
    }
    float denom = 0.f, a0 = 0.f, a1 = 0.f;
    for (int cc = 0; cc < C; ++cc) {
        int slot = (jb + cc) * 32 + bh;
        float w = exp2f(ml[cc].x - M) * ml[cc].y;
        denom += w;
        union { unsigned int u; bf16 hh[2]; } uu;
        uu.u = *(const unsigned int*)(opart + (((size_t)slot * 64 + r64) << 7) + lane * 2);
        a0 += w * (float)uu.hh[0];
        a1 += w * (float)uu.hh[1];
    }
    float rd = 1.0f / denom;
    union { unsigned int u; bf16 hh[2]; } ov;
    ov.hh[0] = (bf16)(a0 * rd);
    ov.hh[1] = (bf16)(a1 * rd);
    *(unsigned int*)(attn + (((size_t)(b << 11) + q) << 11) + h * 128 + lane * 2) = ov.u;
}

// ---------------------------------------------------------------- launch
extern "C" void kernel_launch(void* const* d_in, const int* in_sizes, int n_in,
                              void* d_out, int out_size, void* d_ws, size_t ws_size,
                              hipStream_t stream) {
    const float* hidden = (const float*)d_in[0];
    const float* Wq  = (const float*)d_in[1];
    const float* Wk  = (const float*)d_in[2];
    const float* Wv  = (const float*)d_in[3];
    const float* Wo  = (const float*)d_in[4];
    const float* cqw = (const float*)d_in[5];
    const float* ckw = (const float*)d_in[6];
    const float* cvw = (const float*)d_in[7];
    const float* qnw = (const float*)d_in[8];
    const float* knw = (const float*)d_in[9];

    char* p = (char*)d_ws;
    auto alloc = [&](size_t bytes) { char* r = p; p += (bytes + 255) & ~(size_t)255; return r; };
    bf16*  X    = (bf16*)alloc((size_t)M_ * D_ * 2);       // dead after gemm1 -> opart overlay
    bf16*  Wcat = (bf16*)alloc((size_t)NQKV_ * D_ * 2);    // dead after gemm1 -> opart overlay
    bf16*  Wob  = (bf16*)alloc((size_t)D_ * D_ * 2);
    bf16*  QKV  = (bf16*)alloc((size_t)M_ * NQKV_ * 2);    // dead after canon -> attnb
    bf16*  qfb  = (bf16*)alloc((size_t)B_ * H_ * S_ * DH_ * 2);
    bf16*  kfb  = (bf16*)alloc((size_t)B_ * KVH_ * S_ * DH_ * 2);
    bf16*  vfb  = (bf16*)alloc((size_t)B_ * KVH_ * S_ * DH_ * 2);
    bf16*  vfT  = (bf16*)alloc((size_t)B_ * KVH_ * S_ * DH_ * 2);
    float* cost = (float*)alloc((size_t)S_ * 64 * 4);
    float* sint = (float*)alloc((size_t)S_ * 64 * 4);
    float2* mlb = (float2*)alloc((size_t)NBLK_ * 64 * 8);
    bf16*  opart = X;     // 1920*64*128*2 = 31.5 MB <= X+Wcat (33.5 MB), dead by then
    bf16*  attnb = QKV;   // QKV dead after canon_kernel

    cast_kernel<<<M_ * D_ / 4 / 256, 256, 0, stream>>>(hidden, X, M_ * D_);
    cast_kernel<<<D_ * D_ / 4 / 256, 256, 0, stream>>>(Wq, Wcat, D_ * D_);
    cast_kernel<<<1024 * 2048 / 4 / 256, 256, 0, stream>>>(Wk, Wcat + (size_t)2048 * 2048, 1024 * 2048);
    cast_kernel<<<1024 * 2048 / 4 / 256, 256, 0, stream>>>(Wv, Wcat + (size_t)3072 * 2048, 1024 * 2048);
    cast_kernel<<<D_ * D_ / 4 / 256, 256, 0, stream>>>(Wo, Wob, D_ * D_);
    rope_table<<<S_ * 64 / 256, 256, 0, stream>>>(cost, sint);

    gemm_bt<bf16><<<dim3(NQKV_ / BN, M_ / BM), 256, 0, stream>>>(X, Wcat, QKV, M_, NQKV_, D_);
    canon_kernel<<<M_, 512, 0, stream>>>(QKV, cqw, ckw, cvw, qnw, knw, cost, sint, qfb, kfb, vfb);
    transpose_v<<<dim3(S_ / 64, DH_ / 64, B_ * KVH_), 256, 0, stream>>>(vfb, vfT);
    flash_attn<<<NBLK_, 256, 0, stream>>>(qfb, kfb, vfT, opart, mlb);
    combine_kernel<<<B_ * S_ * H_ / 4, 256, 0, stream>>>(opart, mlb, attnb);
    gemm_bt<float><<<dim3(D_ / BN, M_ / BM), 256, 0, stream>>>(attnb, Wob, (float*)d_out, M_, D_, D_);
}

// Round 6
// 721.075 us; speedup vs baseline: 1.1784x; 1.1784x over previous
//
#include <hip/hip_runtime.h>
#include <hip/hip_bf16.h>

typedef __bf16 bf16;
typedef __bf16 bf16x8 __attribute__((ext_vector_type(8)));
typedef float  floatx4 __attribute__((ext_vector_type(4)));

#define AS1 __attribute__((address_space(1)))
#define AS3 __attribute__((address_space(3)))

#define B_    2
#define S_    2048
#define D_    2048
#define H_    16
#define KVH_  8
#define DH_   128
#define M_    4096      // B_*S_
#define NQKV_ 4096      // D_ + 2*KVH_*DH_

// ---------------------------------------------------------------- cast fp32 -> bf16
__global__ __launch_bounds__(256) void cast_kernel(const float* __restrict__ in,
                                                   bf16* __restrict__ out, int n) {
    int i = (blockIdx.x * blockDim.x + threadIdx.x) * 4;
    if (i < n) {
        float4 v = *(const float4*)(in + i);
        union { bf16 h[4]; double d; } u;
        u.h[0] = (bf16)v.x; u.h[1] = (bf16)v.y; u.h[2] = (bf16)v.z; u.h[3] = (bf16)v.w;
        *(double*)(out + i) = u.d;
    }
}

// ---------------------------------------------------------------- RoPE tables [S][64]
__global__ __launch_bounds__(256) void rope_table(float* __restrict__ cost,
                                                  float* __restrict__ sint) {
    int i = blockIdx.x * blockDim.x + threadIdx.x;   // S_*64 threads
    int t = i >> 6, fi = i & 63;
    float inv = expf(-9.210340371976184f * (float)fi * (1.0f / 64.0f)); // 10000^(-fi/64)
    float ang = (float)t * inv;
    cost[i] = cosf(ang);
    sint[i] = sinf(ang);
}

// ---------------------------------------------------------------- GEMM: C[M,N] = A[M,K] * B[N,K]^T   (bf16 in, fp32 acc, CT out)
#define BM 128
#define BN 128
#define BK 64
template <typename CT>
__global__ __launch_bounds__(256) void gemm_bt(const bf16* __restrict__ A,
                                               const bf16* __restrict__ Bw,
                                               CT* __restrict__ C,
                                               int M, int N, int K) {
    __shared__ __align__(16) bf16 Als[BM * BK];
    __shared__ __align__(16) bf16 Bls[BN * BK];
    int tid  = threadIdx.x;
    int wave = tid >> 6, lane = tid & 63;
    int quad = lane >> 4, l16 = lane & 15;
    int wm = (wave >> 1) << 6;   // 0 / 64
    int wn = (wave & 1) << 6;

    long bm0 = (long)blockIdx.y * BM;
    long bn0 = (long)blockIdx.x * BN;
    const bf16* Ab = A  + bm0 * K;
    const bf16* Bb = Bw + bn0 * K;

    int srow = wave * 32 + (lane >> 3);
    int scol = ((lane & 7) ^ (lane >> 3)) << 3;
    int sdst = (wave * 32 + (lane >> 3)) * BK + ((lane & 7) << 3);

    floatx4 acc[4][4] = {};

    for (int k0 = 0; k0 < K; k0 += BK) {
        #pragma unroll
        for (int i = 0; i < 4; ++i) {
            const bf16* ga = Ab + (long)(srow + i * 8) * K + k0 + scol;
            const bf16* gb = Bb + (long)(srow + i * 8) * K + k0 + scol;
            __builtin_amdgcn_global_load_lds((AS1 const unsigned int*)ga,
                                             (AS3 unsigned int*)(Als + sdst + i * 512), 16, 0, 0);
            __builtin_amdgcn_global_load_lds((AS1 const unsigned int*)gb,
                                             (AS3 unsigned int*)(Bls + sdst + i * 512), 16, 0, 0);
        }
        __syncthreads();
        #pragma unroll
        for (int ks = 0; ks < 2; ++ks) {
            bf16x8 af[4], bfr[4];
            #pragma unroll
            for (int t = 0; t < 4; ++t) {
                int row = wm + t * 16 + l16;
                int g = (ks * 4 + quad) ^ (row & 7);
                af[t] = *(const bf16x8*)(Als + row * BK + (g << 3));
            }
            #pragma unroll
            for (int t = 0; t < 4; ++t) {
                int row = wn + t * 16 + l16;
                int g = (ks * 4 + quad) ^ (row & 7);
                bfr[t] = *(const bf16x8*)(Bls + row * BK + (g << 3));
            }
            #pragma unroll
            for (int mt = 0; mt < 4; ++mt)
                #pragma unroll
                for (int nt = 0; nt < 4; ++nt)
                    acc[mt][nt] = __builtin_amdgcn_mfma_f32_16x16x32_bf16(af[mt], bfr[nt], acc[mt][nt], 0, 0, 0);
        }
        __syncthreads();
    }
    #pragma unroll
    for (int mt = 0; mt < 4; ++mt) {
        #pragma unroll
        for (int nt = 0; nt < 4; ++nt) {
            long row = bm0 + wm + mt * 16 + quad * 4;
            long col = bn0 + wn + nt * 16 + l16;
            #pragma unroll
            for (int r = 0; r < 4; ++r)
                C[(row + r) * N + col] = (CT)acc[mt][nt][r];
        }
    }
}

// ---------------------------------------------------------------- canon_b + RMSNorm + RoPE
__global__ __launch_bounds__(512) void canon_kernel(const bf16* __restrict__ QKV,
                                                    const float* __restrict__ wq,
                                                    const float* __restrict__ wk,
                                                    const float* __restrict__ wv,
                                                    const float* __restrict__ qnw,
                                                    const float* __restrict__ knw,
                                                    const float* __restrict__ cost,
                                                    const float* __restrict__ sint,
                                                    bf16* __restrict__ qf,
                                                    bf16* __restrict__ kf,
                                                    bf16* __restrict__ vf) {
    int row = blockIdx.x;
    int b = row >> 11, t = row & 2047;
    int tid = threadIdx.x;
    int c0 = tid << 3;
    __shared__ float vals[4096];
    __shared__ float rrms[24];

    const float* wrow; int cw;
    if (c0 < 2048)      { wrow = wq; cw = c0; }
    else if (c0 < 3072) { wrow = wk; cw = c0 - 2048; }
    else                { wrow = wv; cw = c0 - 3072; }

    float4 w4[8];
    #pragma unroll
    for (int j = 0; j < 8; ++j) w4[j] = *(const float4*)(wrow + (cw + j) * 4);

    union U8 { float4 v; bf16 h[8]; };
    float acc[8];
    {
        U8 u; u.v = *(const float4*)(QKV + (size_t)row * 4096 + c0);
        #pragma unroll
        for (int j = 0; j < 8; ++j) acc[j] = (float)u.h[j];
    }
    #pragma unroll
    for (int kk = 0; kk < 4; ++kk) {
        int tt = t - kk;
        if (tt >= 0) {
            U8 u; u.v = *(const float4*)(QKV + ((size_t)((b << 11) + tt)) * 4096 + c0);
            #pragma unroll
            for (int j = 0; j < 8; ++j) acc[j] += (&w4[j].x)[kk] * (float)u.h[j];
        }
    }
    #pragma unroll
    for (int j = 0; j < 8; ++j) vals[c0 + j] = acc[j];
    __syncthreads();

    if (tid < 384) {
        int hh = tid >> 4, sub = tid & 15;
        const float* vp = vals + hh * 128 + sub * 8;
        float ss = 0.f;
        #pragma unroll
        for (int j = 0; j < 8; ++j) ss += vp[j] * vp[j];
        ss += __shfl_xor(ss, 1); ss += __shfl_xor(ss, 2);
        ss += __shfl_xor(ss, 4); ss += __shfl_xor(ss, 8);
        if (sub == 0) rrms[hh] = rsqrtf(ss * (1.0f / 128.0f) + 1e-6f);
    }
    __syncthreads();

    if (c0 < 3072) {
        int ch   = (c0 < 2048) ? c0 : c0 - 2048;
        int head = ch >> 7;
        int j0   = ch & 127;
        int hb   = c0 - j0;
        const float* nw = (c0 < 2048) ? qnw : knw;
        float r1 = rrms[c0 >> 7];
        const float* ct = cost + t * 64;
        const float* st = sint + t * 64;
        __align__(16) bf16 outv[8];
        #pragma unroll
        for (int j = 0; j < 8; ++j) {
            int jj = j0 + j;
            float xn = vals[hb + jj] * r1 * nw[jj];
            int pj = (jj < 64) ? jj + 64 : jj - 64;
            float xp = vals[hb + pj] * r1 * nw[pj];
            float rot = (jj < 64) ? -xp : xp;
            int fi = jj & 63;
            outv[j] = (bf16)(xn * ct[fi] + rot * st[fi]);
        }
        bf16* dst = (c0 < 2048)
            ? qf + ((((size_t)b * H_  + head) * S_ + t) << 7) + j0
            : kf + ((((size_t)b * KVH_ + head) * S_ + t) << 7) + j0;
        *(float4*)dst = *(float4*)outv;
    } else {
        int ch = c0 - 3072;
        int head = ch >> 7, j0 = ch & 127;
        __align__(16) bf16 outv[8];
        #pragma unroll
        for (int j = 0; j < 8; ++j) outv[j] = (bf16)acc[j];
        bf16* dst = vf + ((((size_t)b * KVH_ + head) * S_ + t) << 7) + j0;
        *(float4*)dst = *(float4*)outv;
    }
}

// ---------------------------------------------------------------- V transpose: [bk][S][128] -> [bk][128][S]
__global__ __launch_bounds__(256) void transpose_v(const bf16* __restrict__ vf,
                                                   bf16* __restrict__ vfT) {
    __shared__ __align__(16) bf16 tile[64][72];
    int bk = blockIdx.z;
    int t0 = blockIdx.x * 64;
    int d0 = blockIdx.y * 64;
    int tid = threadIdx.x;
    const bf16* src = vf + ((size_t)bk * S_ << 7);
    {
        int r = tid >> 3, cs = (tid & 7) << 3;
        #pragma unroll
        for (int p = 0; p < 2; ++p)
            *(float4*)(&tile[r + p * 32][cs]) =
                *(const float4*)(src + (size_t)(t0 + r + p * 32) * 128 + d0 + cs);
    }
    __syncthreads();
    {
        int dr = tid >> 3, ts = (tid & 7) << 3;
        #pragma unroll
        for (int p = 0; p < 2; ++p) {
            __align__(16) bf16 outv[8];
            #pragma unroll
            for (int j = 0; j < 8; ++j) outv[j] = tile[ts + j][dr + p * 32];
            *(float4*)(vfT + ((size_t)bk * 128 + d0 + dr + p * 32) * S_ + t0 + ts) = *(float4*)outv;
        }
    }
}

// ---------------------------------------------------------------- flash attention (causal, GQA)
// Barrier-free AND shuffle-free: RMSNorm guarantees |q.k|*scale*log2e <= 16.3,
// so exp2 without max-subtraction cannot overflow -> no online max, no o-rescale,
// no cross-lane ops in the loop. l is a per-lane partial sum reduced once at end.
__global__ __launch_bounds__(256) void flash_attn(const bf16* __restrict__ qf,
                                                  const bf16* __restrict__ kf,
                                                  const bf16* __restrict__ vfT,
                                                  bf16* __restrict__ attn) {
    __shared__ __align__(16) bf16 Pls[4][16][72];  // per-wave P, +8 pad
    int lid  = blockIdx.x;                         // 0..1023
    int pair = lid & 15;                           // (b*8+kvh) -> stable XCD via lid%8
    int b    = pair >> 3, kvh = pair & 7;
    int inner = lid >> 4;                          // 0..63
    int qt   = 31 - (inner >> 1);                  // longest q-tiles first
    int h    = kvh * 2 + (inner & 1);
    int tid = threadIdx.x, wave = tid >> 6, lane = tid & 63;
    int quad = lane >> 4, l16 = lane & 15;
    int qrow0 = (qt << 6) + (wave << 4);           // wave's 16 q rows

    const bf16* kbase = kf  + (((size_t)b * KVH_ + kvh) * S_ << 7);
    const bf16* vbase = vfT + (((size_t)b * KVH_ + kvh) << 7) * S_;

    bf16x8 aq[4];   // Q A-frags over d (4 * 32)
    {
        const bf16* qr = qf + ((((size_t)b * H_ + h) * S_ + qrow0 + l16) << 7) + (quad << 3);
        #pragma unroll
        for (int ks = 0; ks < 4; ++ks) aq[ks] = *(const bf16x8*)(qr + ks * 32);
    }
    floatx4 o[8] = {};
    float l_i[4] = {0.f, 0.f, 0.f, 0.f};           // per-lane partial denominators
    const float scl2 = 0.08838834764831845f * 1.4426950408889634f;  // scale*log2(e)

    int ktiles = qt + 1;
    for (int kt = 0; kt < ktiles; ++kt) {
        int kb = kt << 6;
        // S = Q K^T (K B-frags straight from global, L2-resident)
        floatx4 sc[4] = {};
        #pragma unroll
        for (int nt = 0; nt < 4; ++nt) {
            const bf16* kr = kbase + ((size_t)(kb + nt * 16 + l16) << 7) + (quad << 3);
            #pragma unroll
            for (int ks = 0; ks < 4; ++ks) {
                bf16x8 kb8 = *(const bf16x8*)(kr + ks * 32);
                sc[nt] = __builtin_amdgcn_mfma_f32_16x16x32_bf16(aq[ks], kb8, sc[nt], 0, 0, 0);
            }
        }
        // prefetch V frags for ks=0 half (independent of softmax)
        bf16x8 vpre[8];
        #pragma unroll
        for (int dnt = 0; dnt < 8; ++dnt)
            vpre[dnt] = *(const bf16x8*)(vbase + (size_t)(dnt * 16 + l16) * S_ + kb + (quad << 3));
        // p = exp2(s*scl2), masked to 0; accumulate per-lane l; no shuffles
        int qr0 = qrow0 + (quad << 2);
        #pragma unroll
        for (int nt = 0; nt < 4; ++nt) {
            int key = kb + nt * 16 + l16;
            #pragma unroll
            for (int r = 0; r < 4; ++r) {
                float pv = exp2f(sc[nt][r] * scl2);
                pv = (key <= qr0 + r) ? pv : 0.f;
                sc[nt][r] = pv;
                l_i[r] += pv;
                Pls[wave][(quad << 2) + r][nt * 16 + l16] = (bf16)pv;
            }
        }
        // O += P V  (ks=0 from prefetch, ks=1 inline)
        {
            bf16x8 pa = *(const bf16x8*)(&Pls[wave][l16][(quad << 3)]);
            #pragma unroll
            for (int dnt = 0; dnt < 8; ++dnt)
                o[dnt] = __builtin_amdgcn_mfma_f32_16x16x32_bf16(pa, vpre[dnt], o[dnt], 0, 0, 0);
            bf16x8 pb = *(const bf16x8*)(&Pls[wave][l16][32 + (quad << 3)]);
            #pragma unroll
            for (int dnt = 0; dnt < 8; ++dnt) {
                bf16x8 vb = *(const bf16x8*)(vbase + (size_t)(dnt * 16 + l16) * S_
                                             + kb + 32 + (quad << 3));
                o[dnt] = __builtin_amdgcn_mfma_f32_16x16x32_bf16(pb, vb, o[dnt], 0, 0, 0);
            }
        }
    }
    // epilogue: one cross-lane reduction of l per row, then write
    #pragma unroll
    for (int r = 0; r < 4; ++r) {
        float l = l_i[r];
        l += __shfl_xor(l, 1); l += __shfl_xor(l, 2);
        l += __shfl_xor(l, 4); l += __shfl_xor(l, 8);
        l_i[r] = 1.0f / l;
    }
    #pragma unroll
    for (int dnt = 0; dnt < 8; ++dnt) {
        #pragma unroll
        for (int r = 0; r < 4; ++r) {
            size_t row = (size_t)b * S_ + qrow0 + (quad << 2) + r;
            attn[row * D_ + h * DH_ + dnt * 16 + l16] = (bf16)(o[dnt][r] * l_i[r]);
        }
    }
}

// ---------------------------------------------------------------- launch
extern "C" void kernel_launch(void* const* d_in, const int* in_sizes, int n_in,
                              void* d_out, int out_size, void* d_ws, size_t ws_size,
                              hipStream_t stream) {
    const float* hidden = (const float*)d_in[0];
    const float* Wq  = (const float*)d_in[1];
    const float* Wk  = (const float*)d_in[2];
    const float* Wv  = (const float*)d_in[3];
    const float* Wo  = (const float*)d_in[4];
    const float* cqw = (const float*)d_in[5];
    const float* ckw = (const float*)d_in[6];
    const float* cvw = (const float*)d_in[7];
    const float* qnw = (const float*)d_in[8];
    const float* knw = (const float*)d_in[9];

    char* p = (char*)d_ws;
    auto alloc = [&](size_t bytes) { char* r = p; p += (bytes + 255) & ~(size_t)255; return r; };
    bf16*  X    = (bf16*)alloc((size_t)M_ * D_ * 2);
    bf16*  Wcat = (bf16*)alloc((size_t)NQKV_ * D_ * 2);
    bf16*  Wob  = (bf16*)alloc((size_t)D_ * D_ * 2);
    bf16*  QKV  = (bf16*)alloc((size_t)M_ * NQKV_ * 2);
    bf16*  qfb  = (bf16*)alloc((size_t)B_ * H_ * S_ * DH_ * 2);
    bf16*  kfb  = (bf16*)alloc((size_t)B_ * KVH_ * S_ * DH_ * 2);
    bf16*  vfb  = (bf16*)alloc((size_t)B_ * KVH_ * S_ * DH_ * 2);
    bf16*  vfT  = (bf16*)alloc((size_t)B_ * KVH_ * S_ * DH_ * 2);
    float* cost = (float*)alloc((size_t)S_ * 64 * 4);
    float* sint = (float*)alloc((size_t)S_ * 64 * 4);
    bf16*  attnb = QKV;   // QKV dead after canon_kernel

    cast_kernel<<<M_ * D_ / 4 / 256, 256, 0, stream>>>(hidden, X, M_ * D_);
    cast_kernel<<<D_ * D_ / 4 / 256, 256, 0, stream>>>(Wq, Wcat, D_ * D_);
    cast_kernel<<<1024 * 2048 / 4 / 256, 256, 0, stream>>>(Wk, Wcat + (size_t)2048 * 2048, 1024 * 2048);
    cast_kernel<<<1024 * 2048 / 4 / 256, 256, 0, stream>>>(Wv, Wcat + (size_t)3072 * 2048, 1024 * 2048);
    cast_kernel<<<D_ * D_ / 4 / 256, 256, 0, stream>>>(Wo, Wob, D_ * D_);
    rope_table<<<S_ * 64 / 256, 256, 0, stream>>>(cost, sint);

    gemm_bt<bf16><<<dim3(NQKV_ / BN, M_ / BM), 256, 0, stream>>>(X, Wcat, QKV, M_, NQKV_, D_);
    canon_kernel<<<M_, 512, 0, stream>>>(QKV, cqw, ckw, cvw, qnw, knw, cost, sint, qfb, kfb, vfb);
    transpose_v<<<dim3(S_ / 64, DH_ / 64, B_ * KVH_), 256, 0, stream>>>(vfb, vfT);
    flash_attn<<<1024, 256, 0, stream>>>(qfb, kfb, vfT, attnb);
    gemm_bt<float><<<dim3(D_ / BN, M_ / BM), 256, 0, stream>>>(attnb, Wob, (float*)d_out, M_, D_, D_);
}

// Round 7
// 573.181 us; speedup vs baseline: 1.4824x; 1.2580x over previous
//
#include <hip/hip_runtime.h>
#include <hip/hip_bf16.h>

typedef __bf16 bf16;
typedef __bf16 bf16x8 __attribute__((ext_vector_type(8)));
typedef float  floatx4 __attribute__((ext_vector_type(4)));

#define AS1 __attribute__((address_space(1)))
#define AS3 __attribute__((address_space(3)))

#define B_    2
#define S_    2048
#define D_    2048
#define H_    16
#define KVH_  8
#define DH_   128
#define M_    4096      // B_*S_
#define NQKV_ 4096      // D_ + 2*KVH_*DH_

// ---------------------------------------------------------------- cast fp32 -> bf16
__global__ __launch_bounds__(256) void cast_kernel(const float* __restrict__ in,
                                                   bf16* __restrict__ out, int n) {
    int i = (blockIdx.x * blockDim.x + threadIdx.x) * 4;
    if (i < n) {
        float4 v = *(const float4*)(in + i);
        union { bf16 h[4]; double d; } u;
        u.h[0] = (bf16)v.x; u.h[1] = (bf16)v.y; u.h[2] = (bf16)v.z; u.h[3] = (bf16)v.w;
        *(double*)(out + i) = u.d;
    }
}

// ---------------------------------------------------------------- RoPE tables [S][64]
__global__ __launch_bounds__(256) void rope_table(float* __restrict__ cost,
                                                  float* __restrict__ sint) {
    int i = blockIdx.x * blockDim.x + threadIdx.x;   // S_*64 threads
    int t = i >> 6, fi = i & 63;
    float inv = expf(-9.210340371976184f * (float)fi * (1.0f / 64.0f)); // 10000^(-fi/64)
    float ang = (float)t * inv;
    cost[i] = cosf(ang);
    sint[i] = sinf(ang);
}

// ---------------------------------------------------------------- GEMM: C[M,N] = A[M,K] * B[N,K]^T   (bf16 in, fp32 acc, CT out)
#define BM 128
#define BN 128
#define BK 64
template <typename CT>
__global__ __launch_bounds__(256) void gemm_bt(const bf16* __restrict__ A,
                                               const bf16* __restrict__ Bw,
                                               CT* __restrict__ C,
                                               int M, int N, int K) {
    __shared__ __align__(16) bf16 Als[BM * BK];
    __shared__ __align__(16) bf16 Bls[BN * BK];
    int tid  = threadIdx.x;
    int wave = tid >> 6, lane = tid & 63;
    int quad = lane >> 4, l16 = lane & 15;
    int wm = (wave >> 1) << 6;   // 0 / 64
    int wn = (wave & 1) << 6;

    long bm0 = (long)blockIdx.y * BM;
    long bn0 = (long)blockIdx.x * BN;
    const bf16* Ab = A  + bm0 * K;
    const bf16* Bb = Bw + bn0 * K;

    int srow = wave * 32 + (lane >> 3);
    int scol = ((lane & 7) ^ (lane >> 3)) << 3;
    int sdst = (wave * 32 + (lane >> 3)) * BK + ((lane & 7) << 3);

    floatx4 acc[4][4] = {};

    for (int k0 = 0; k0 < K; k0 += BK) {
        #pragma unroll
        for (int i = 0; i < 4; ++i) {
            const bf16* ga = Ab + (long)(srow + i * 8) * K + k0 + scol;
            const bf16* gb = Bb + (long)(srow + i * 8) * K + k0 + scol;
            __builtin_amdgcn_global_load_lds((AS1 const unsigned int*)ga,
                                             (AS3 unsigned int*)(Als + sdst + i * 512), 16, 0, 0);
            __builtin_amdgcn_global_load_lds((AS1 const unsigned int*)gb,
                                             (AS3 unsigned int*)(Bls + sdst + i * 512), 16, 0, 0);
        }
        __syncthreads();
        #pragma unroll
        for (int ks = 0; ks < 2; ++ks) {
            bf16x8 af[4], bfr[4];
            #pragma unroll
            for (int t = 0; t < 4; ++t) {
                int row = wm + t * 16 + l16;
                int g = (ks * 4 + quad) ^ (row & 7);
                af[t] = *(const bf16x8*)(Als + row * BK + (g << 3));
            }
            #pragma unroll
            for (int t = 0; t < 4; ++t) {
                int row = wn + t * 16 + l16;
                int g = (ks * 4 + quad) ^ (row & 7);
                bfr[t] = *(const bf16x8*)(Bls + row * BK + (g << 3));
            }
            #pragma unroll
            for (int mt = 0; mt < 4; ++mt)
                #pragma unroll
                for (int nt = 0; nt < 4; ++nt)
                    acc[mt][nt] = __builtin_amdgcn_mfma_f32_16x16x32_bf16(af[mt], bfr[nt], acc[mt][nt], 0, 0, 0);
        }
        __syncthreads();
    }
    #pragma unroll
    for (int mt = 0; mt < 4; ++mt) {
        #pragma unroll
        for (int nt = 0; nt < 4; ++nt) {
            long row = bm0 + wm + mt * 16 + quad * 4;
            long col = bn0 + wn + nt * 16 + l16;
            #pragma unroll
            for (int r = 0; r < 4; ++r)
                C[(row + r) * N + col] = (CT)acc[mt][nt][r];
        }
    }
}

// ---------------------------------------------------------------- canon_b + RMSNorm + RoPE
// Writes Q and K in FRAG-LINEAR layout (MFMA fragment order, lane-contiguous):
//   qf: [b][h][S/16 rowtile][ks:4][lane:64][8]
//   kf: [b][kvh][S/64 ktile][nt:4][ks:4][lane:64][8]   (lane = quad*16 + (t&15))
// V stays row-major (vf), repacked by repack_v.
__global__ __launch_bounds__(512) void canon_kernel(const bf16* __restrict__ QKV,
                                                    const float* __restrict__ wq,
                                                    const float* __restrict__ wk,
                                                    const float* __restrict__ wv,
                                                    const float* __restrict__ qnw,
                                                    const float* __restrict__ knw,
                                                    const float* __restrict__ cost,
                                                    const float* __restrict__ sint,
                                                    bf16* __restrict__ qf,
                                                    bf16* __restrict__ kf,
                                                    bf16* __restrict__ vf) {
    int row = blockIdx.x;
    int b = row >> 11, t = row & 2047;
    int tid = threadIdx.x;
    int c0 = tid << 3;
    __shared__ float vals[4096];
    __shared__ float rrms[24];

    const float* wrow; int cw;
    if (c0 < 2048)      { wrow = wq; cw = c0; }
    else if (c0 < 3072) { wrow = wk; cw = c0 - 2048; }
    else                { wrow = wv; cw = c0 - 3072; }

    float4 w4[8];
    #pragma unroll
    for (int j = 0; j < 8; ++j) w4[j] = *(const float4*)(wrow + (cw + j) * 4);

    union U8 { float4 v; bf16 h[8]; };
    float acc[8];
    {
        U8 u; u.v = *(const float4*)(QKV + (size_t)row * 4096 + c0);
        #pragma unroll
        for (int j = 0; j < 8; ++j) acc[j] = (float)u.h[j];
    }
    #pragma unroll
    for (int kk = 0; kk < 4; ++kk) {
        int tt = t - kk;
        if (tt >= 0) {
            U8 u; u.v = *(const float4*)(QKV + ((size_t)((b << 11) + tt)) * 4096 + c0);
            #pragma unroll
            for (int j = 0; j < 8; ++j) acc[j] += (&w4[j].x)[kk] * (float)u.h[j];
        }
    }
    #pragma unroll
    for (int j = 0; j < 8; ++j) vals[c0 + j] = acc[j];
    __syncthreads();

    if (tid < 384) {
        int hh = tid >> 4, sub = tid & 15;
        const float* vp = vals + hh * 128 + sub * 8;
        float ss = 0.f;
        #pragma unroll
        for (int j = 0; j < 8; ++j) ss += vp[j] * vp[j];
        ss += __shfl_xor(ss, 1); ss += __shfl_xor(ss, 2);
        ss += __shfl_xor(ss, 4); ss += __shfl_xor(ss, 8);
        if (sub == 0) rrms[hh] = rsqrtf(ss * (1.0f / 128.0f) + 1e-6f);
    }
    __syncthreads();

    if (c0 < 3072) {
        int ch   = (c0 < 2048) ? c0 : c0 - 2048;
        int head = ch >> 7;
        int j0   = ch & 127;
        int hb   = c0 - j0;
        const float* nw = (c0 < 2048) ? qnw : knw;
        float r1 = rrms[c0 >> 7];
        const float* ct = cost + t * 64;
        const float* st = sint + t * 64;
        __align__(16) bf16 outv[8];
        #pragma unroll
        for (int j = 0; j < 8; ++j) {
            int jj = j0 + j;
            float xn = vals[hb + jj] * r1 * nw[jj];
            int pj = (jj < 64) ? jj + 64 : jj - 64;
            float xp = vals[hb + pj] * r1 * nw[pj];
            float rot = (jj < 64) ? -xp : xp;
            int fi = jj & 63;
            outv[j] = (bf16)(xn * ct[fi] + rot * st[fi]);
        }
        int ks = j0 >> 5, qd = (j0 >> 3) & 3;      // frag coords from d-offset
        bf16* dst;
        if (c0 < 2048) {
            size_t idx = ((((size_t)(b * H_ + head) * 128 + (t >> 4)) * 4 + ks) * 64
                          + qd * 16 + (t & 15)) << 3;
            dst = qf + idx;
        } else {
            size_t idx = ((((size_t)(b * KVH_ + head) * 32 + (t >> 6)) * 16
                          + ((t >> 4) & 3) * 4 + ks) * 64 + qd * 16 + (t & 15)) << 3;
            dst = kf + idx;
        }
        *(float4*)dst = *(float4*)outv;
    } else {
        int ch = c0 - 3072;
        int head = ch >> 7, j0 = ch & 127;
        __align__(16) bf16 outv[8];
        #pragma unroll
        for (int j = 0; j < 8; ++j) outv[j] = (bf16)acc[j];
        bf16* dst = vf + ((((size_t)b * KVH_ + head) * S_ + t) << 7) + j0;
        *(float4*)dst = *(float4*)outv;
    }
}

// ---------------------------------------------------------------- V repack: row-major -> frag-linear
// vf[bk][S][128] -> vfrag[bk][S/64 ktile][ks:2][dnt:8][lane:64][8]
//   element (t,d): kt=t>>6, tt=t&63, ks=tt>>5, quad=(tt>>3)&3, j=tt&7, lane=quad*16+(d&15)
__global__ __launch_bounds__(256) void repack_v(const bf16* __restrict__ vf,
                                                bf16* __restrict__ vfrag) {
    __shared__ __align__(16) bf16 tile[64 * 136];  // [t][d], stride 136
    int kt = blockIdx.x, bk = blockIdx.y;
    int tid = threadIdx.x;
    const bf16* src = vf + (((size_t)bk * S_ + (kt << 6)) << 7);
    #pragma unroll
    for (int p = 0; p < 4; ++p) {
        int c = tid + p * 256;                 // 1024 chunks of 8
        int tt = c >> 4, d0 = (c & 15) << 3;
        *(float4*)(&tile[tt * 136 + d0]) = *(const float4*)(src + ((size_t)tt << 7) + d0);
    }
    __syncthreads();
    bf16* dst = vfrag + (((size_t)bk * 32 + kt) << 13);   // 16 frags * 512
    #pragma unroll
    for (int p = 0; p < 4; ++p) {
        int c = tid + p * 256;                 // frag-chunk id: ks*8*64 + dnt*64 + lane
        int ks = c >> 9, rem = c & 511;
        int dnt = rem >> 6, lane = rem & 63;
        int quad = lane >> 4, l16 = lane & 15;
        __align__(16) bf16 outv[8];
        #pragma unroll
        for (int j = 0; j < 8; ++j)
            outv[j] = tile[(ks * 32 + quad * 8 + j) * 136 + dnt * 16 + l16];
        *(float4*)(dst + ((size_t)c << 3)) = *(float4*)outv;
    }
}

// ---------------------------------------------------------------- flash attention (causal, GQA)
// Frag-linear inputs: every load is base + lane*16B (fully coalesced 1KB).
// Barrier-free, shuffle-free (RMSNorm bounds |s|*log2e <= 16.3 -> no max needed).
__global__ __launch_bounds__(256) void flash_attn(const bf16* __restrict__ qf,
                                                  const bf16* __restrict__ kf,
                                                  const bf16* __restrict__ vfrag,
                                                  bf16* __restrict__ attn) {
    __shared__ __align__(16) bf16 Pls[4][16][72];
    int lid  = blockIdx.x;                         // 0..1023
    int pair = lid & 15;                           // (b*8+kvh) -> stable XCD via lid%8
    int b    = pair >> 3, kvh = pair & 7;
    int inner = lid >> 4;                          // 0..63
    int qt   = 31 - (inner >> 1);                  // longest q-tiles first
    int h    = kvh * 2 + (inner & 1);
    int tid = threadIdx.x, wave = tid >> 6, lane = tid & 63;
    int quad = lane >> 4, l16 = lane & 15;
    int qrow0 = (qt << 6) + (wave << 4);

    const bf16* kfp = kf    + (((size_t)b * KVH_ + kvh) << 18);   // 32 kt * 8192
    const bf16* vfp = vfrag + (((size_t)b * KVH_ + kvh) << 18);
    const bf16* qfp = qf    + ((((size_t)(b * H_ + h) * 128 + (qt << 2) + wave)) << 11);

    bf16x8 aq[4];
    #pragma unroll
    for (int ks = 0; ks < 4; ++ks)
        aq[ks] = *(const bf16x8*)(qfp + (ks << 9) + (lane << 3));

    floatx4 o[8] = {};
    float l_i[4] = {0.f, 0.f, 0.f, 0.f};
    const float scl2 = 0.08838834764831845f * 1.4426950408889634f;  // scale*log2(e)

    int ktiles = qt + 1;
    for (int kt = 0; kt < ktiles; ++kt) {
        int kb = kt << 6;
        const bf16* ktk = kfp + ((size_t)kt << 13);
        const bf16* ktv = vfp + ((size_t)kt << 13);
        // S = Q K^T  (each frag load: lane-contiguous 1KB)
        floatx4 sc[4] = {};
        #pragma unroll
        for (int nt = 0; nt < 4; ++nt) {
            #pragma unroll
            for (int ks = 0; ks < 4; ++ks) {
                bf16x8 kb8 = *(const bf16x8*)(ktk + ((nt * 4 + ks) << 9) + (lane << 3));
                sc[nt] = __builtin_amdgcn_mfma_f32_16x16x32_bf16(aq[ks], kb8, sc[nt], 0, 0, 0);
            }
        }
        // prefetch V ks=0 frags (independent of softmax)
        bf16x8 vpre[8];
        #pragma unroll
        for (int dnt = 0; dnt < 8; ++dnt)
            vpre[dnt] = *(const bf16x8*)(ktv + ((size_t)dnt << 9) + (lane << 3));
        // p = exp2(s*scl2) masked; per-lane l; no cross-lane ops
        int qr0 = qrow0 + (quad << 2);
        #pragma unroll
        for (int nt = 0; nt < 4; ++nt) {
            int key = kb + nt * 16 + l16;
            #pragma unroll
            for (int r = 0; r < 4; ++r) {
                float pv = exp2f(sc[nt][r] * scl2);
                pv = (key <= qr0 + r) ? pv : 0.f;
                l_i[r] += pv;
                Pls[wave][(quad << 2) + r][nt * 16 + l16] = (bf16)pv;
            }
        }
        // O += P V
        {
            bf16x8 pa = *(const bf16x8*)(&Pls[wave][l16][(quad << 3)]);
            #pragma unroll
            for (int dnt = 0; dnt < 8; ++dnt)
                o[dnt] = __builtin_amdgcn_mfma_f32_16x16x32_bf16(pa, vpre[dnt], o[dnt], 0, 0, 0);
            bf16x8 pb = *(const bf16x8*)(&Pls[wave][l16][32 + (quad << 3)]);
            #pragma unroll
            for (int dnt = 0; dnt < 8; ++dnt) {
                bf16x8 vb = *(const bf16x8*)(ktv + ((size_t)(8 + dnt) << 9) + (lane << 3));
                o[dnt] = __builtin_amdgcn_mfma_f32_16x16x32_bf16(pb, vb, o[dnt], 0, 0, 0);
            }
        }
    }
    // epilogue
    #pragma unroll
    for (int r = 0; r < 4; ++r) {
        float l = l_i[r];
        l += __shfl_xor(l, 1); l += __shfl_xor(l, 2);
        l += __shfl_xor(l, 4); l += __shfl_xor(l, 8);
        l_i[r] = 1.0f / l;
    }
    #pragma unroll
    for (int dnt = 0; dnt < 8; ++dnt) {
        #pragma unroll
        for (int r = 0; r < 4; ++r) {
            size_t row = (size_t)b * S_ + qrow0 + (quad << 2) + r;
            attn[row * D_ + h * DH_ + dnt * 16 + l16] = (bf16)(o[dnt][r] * l_i[r]);
        }
    }
}

// ---------------------------------------------------------------- launch
extern "C" void kernel_launch(void* const* d_in, const int* in_sizes, int n_in,
                              void* d_out, int out_size, void* d_ws, size_t ws_size,
                              hipStream_t stream) {
    const float* hidden = (const float*)d_in[0];
    const float* Wq  = (const float*)d_in[1];
    const float* Wk  = (const float*)d_in[2];
    const float* Wv  = (const float*)d_in[3];
    const float* Wo  = (const float*)d_in[4];
    const float* cqw = (const float*)d_in[5];
    const float* ckw = (const float*)d_in[6];
    const float* cvw = (const float*)d_in[7];
    const float* qnw = (const float*)d_in[8];
    const float* knw = (const float*)d_in[9];

    char* p = (char*)d_ws;
    auto alloc = [&](size_t bytes) { char* r = p; p += (bytes + 255) & ~(size_t)255; return r; };
    bf16*  X    = (bf16*)alloc((size_t)M_ * D_ * 2);
    bf16*  Wcat = (bf16*)alloc((size_t)NQKV_ * D_ * 2);
    bf16*  Wob  = (bf16*)alloc((size_t)D_ * D_ * 2);
    bf16*  QKV  = (bf16*)alloc((size_t)M_ * NQKV_ * 2);
    bf16*  qfb  = (bf16*)alloc((size_t)B_ * H_ * S_ * DH_ * 2);   // frag-linear Q
    bf16*  kfb  = (bf16*)alloc((size_t)B_ * KVH_ * S_ * DH_ * 2); // frag-linear K
    bf16*  vfb  = (bf16*)alloc((size_t)B_ * KVH_ * S_ * DH_ * 2); // row-major V
    bf16*  vfr  = (bf16*)alloc((size_t)B_ * KVH_ * S_ * DH_ * 2); // frag-linear V
    float* cost = (float*)alloc((size_t)S_ * 64 * 4);
    float* sint = (float*)alloc((size_t)S_ * 64 * 4);
    bf16*  attnb = QKV;   // QKV dead after canon_kernel

    cast_kernel<<<M_ * D_ / 4 / 256, 256, 0, stream>>>(hidden, X, M_ * D_);
    cast_kernel<<<D_ * D_ / 4 / 256, 256, 0, stream>>>(Wq, Wcat, D_ * D_);
    cast_kernel<<<1024 * 2048 / 4 / 256, 256, 0, stream>>>(Wk, Wcat + (size_t)2048 * 2048, 1024 * 2048);
    cast_kernel<<<1024 * 2048 / 4 / 256, 256, 0, stream>>>(Wv, Wcat + (size_t)3072 * 2048, 1024 * 2048);
    cast_kernel<<<D_ * D_ / 4 / 256, 256, 0, stream>>>(Wo, Wob, D_ * D_);
    rope_table<<<S_ * 64 / 256, 256, 0, stream>>>(cost, sint);

    gemm_bt<bf16><<<dim3(NQKV_ / BN, M_ / BM), 256, 0, stream>>>(X, Wcat, QKV, M_, NQKV_, D_);
    canon_kernel<<<M_, 512, 0, stream>>>(QKV, cqw, ckw, cvw, qnw, knw, cost, sint, qfb, kfb, vfb);
    repack_v<<<dim3(S_ / 64, B_ * KVH_), 256, 0, stream>>>(vfb, vfr);
    flash_attn<<<1024, 256, 0, stream>>>(qfb, kfb, vfr, attnb);
    gemm_bt<float><<<dim3(D_ / BN, M_ / BM), 256, 0, stream>>>(attnb, Wob, (float*)d_out, M_, D_, D_);
}